// Round 5
// baseline (507.718 us; speedup 1.0000x reference)
//
#include <hip/hip_runtime.h>
#include <stdint.h>

typedef _Float16 half8 __attribute__((ext_vector_type(8)));
typedef _Float16 half4v __attribute__((ext_vector_type(4)));
typedef float floatx4 __attribute__((ext_vector_type(4)));
typedef float floatx16 __attribute__((ext_vector_type(16)));

#define TT 4096
#define DH 512

#define WAITVM(n) asm volatile("s_waitcnt vmcnt(" #n ")" ::: "memory")
#define WAITLGKM() asm volatile("s_waitcnt lgkmcnt(0)" ::: "memory")
#define BAR() __builtin_amdgcn_s_barrier()
#define FENCE() asm volatile("" ::: "memory")

__device__ __forceinline__ unsigned short f2h(float f) {
    union { _Float16 h; unsigned short u; } v;
    v.h = (_Float16)f;
    return v.u;
}

// ---------- kernel 1: normalize right half of x -> xn (fp16), one wave per row ----------
__global__ void norm_k(const float* __restrict__ x, unsigned short* __restrict__ xn) {
    const int w = threadIdx.x >> 6, l = threadIdx.x & 63;
    const int row = blockIdx.x * 4 + w;              // 0 .. B*T-1
    const float* src = x + (size_t)row * 1024 + 512 + l * 8;
    floatx4 a = *(const floatx4*)src;
    floatx4 c = *(const floatx4*)(src + 4);
    float s = a[0]*a[0] + a[1]*a[1] + a[2]*a[2] + a[3]*a[3]
            + c[0]*c[0] + c[1]*c[1] + c[2]*c[2] + c[3]*c[3];
    #pragma unroll
    for (int off = 32; off > 0; off >>= 1) s += __shfl_xor(s, off);
    const float scale = 1.0f / fmaxf(sqrtf(s), 1e-12f);
    float v[8] = {a[0], a[1], a[2], a[3], c[0], c[1], c[2], c[3]};
    uint32_t pk[4];
    #pragma unroll
    for (int i = 0; i < 4; i++)
        pk[i] = (uint32_t)f2h(v[2*i] * scale) | ((uint32_t)f2h(v[2*i+1] * scale) << 16);
    uint4 o; o.x = pk[0]; o.y = pk[1]; o.z = pk[2]; o.w = pk[3];
    *(uint4*)(xn + (size_t)row * DH + l * 8) = o;
}

// ---------- kernel 2: xnT[b][d][t] = xn[b][t][d], 64x64 LDS tile transpose ----------
__global__ void transpose_k(const unsigned short* __restrict__ xn,
                            unsigned short* __restrict__ xnT) {
    __shared__ __align__(16) unsigned short tile[64 * 72];  // +8 pad
    const int b = blockIdx.z;
    const int t0 = blockIdx.x * 64, d0 = blockIdx.y * 64;
    const int tid = threadIdx.x;
    #pragma unroll
    for (int i = 0; i < 2; i++) {
        int c = i * 256 + tid;
        int tr = c >> 3, d8 = c & 7;
        uint4 vv = *(const uint4*)(xn + ((size_t)(b * TT + t0 + tr) * DH + d0 + d8 * 8));
        *(uint4*)&tile[tr * 72 + d8 * 8] = vv;
    }
    __syncthreads();
    #pragma unroll
    for (int i = 0; i < 2; i++) {
        int c = i * 256 + tid;
        int dd = c >> 3, t8 = c & 7;
        uint32_t pk[4];
        #pragma unroll
        for (int k = 0; k < 4; k++) {
            uint32_t h0 = tile[(t8 * 8 + 2 * k    ) * 72 + dd];
            uint32_t h1 = tile[(t8 * 8 + 2 * k + 1) * 72 + dd];
            pk[k] = h0 | (h1 << 16);
        }
        uint4 o; o.x = pk[0]; o.y = pk[1]; o.z = pk[2]; o.w = pk[3];
        *(uint4*)(xnT + ((size_t)(b * DH + d0 + dd) * TT + t0 + t8 * 8)) = o;
    }
}

// ---------- kernel 3: wave-specialized fused kernel ----------
// 512 threads = 8 waves; 2 barriers/phase, 65 phases.
// S-group (waves 0-3, K-quarter dh=w, d in [w*128, w*128+128)):
//   slot1: full S^T[64 kk][64 q] partial over its K-quarter: per ks 2 A-reads
//   (rows m32, 32+m32) feed 4 mfma (ni=0,1). qf[2][8]=64 VGPR. Writes Sred[w].
//   slot2: restage kn[t+1] FIRST, then reduce 4 partials for q-rows w*16..+16,
//   *V, write W[t&1]; prefetch V[t+1].
// C-group (waves 4-7, d-slice (w-4)*128): phase t computes s3 for tile t-1:
//   kt register loads at barA (land during slot1), W[(t-1)&1] reads after barB,
//   32 mfma into persistent acc (128 AGPR).
// Register budget: arch = max(S~120, C~110) <= 128, agpr = 128 -> no spill.
__global__ __launch_bounds__(512, 2) void fused_k(
    const unsigned short* __restrict__ xn, const unsigned short* __restrict__ xnT,
    const float* __restrict__ V, const float* __restrict__ bias,
    const float* __restrict__ x, float* __restrict__ out)
{
    __shared__ __align__(16) unsigned short smem[59392];   // 116 KiB
    unsigned short* knL   = smem;            // [64 kk][512 d], chunk16 ^ (kk&7)
    unsigned short* SredL = smem + 32768;    // [4 dh][64 q][68 pad] fp16 (no xor; stride breaks banks)
    unsigned short* Wl    = smem + 50176;    // [2 buf][64 q][72], unit16B ^ ((q>>3)&3)<<1

    const int tid = threadIdx.x;
    const int w = tid >> 6, l = tid & 63;
    const int h = l >> 5, m32 = l & 31;

    // XCD-aware swizzle
    const int flat = blockIdx.y * 64 + blockIdx.x;
    const int work = (flat & 7) * 32 + (flat >> 3);
    const int b = work >> 6, qt = work & 63;
    const int q0 = qt * 64;

    const unsigned short* xnb = xn  + (size_t)b * TT * DH;
    const unsigned short* xtb = xnT + (size_t)b * DH * TT;

    if (w < 4) {
        // ================= S-group: K-quarter dh = w =================
        const int qh = l & 15, kc = l >> 4;          // slot2 mapping: q-row, kk-chunk16
        const float* vptr = V + (size_t)(q0 + w * 16 + qh) * TT + kc * 16;

        // Q fragments: B-operand, lane q = ni*32+m32, k = w*128 + ks*16 + h*8 + j
        half8 qf[2][8];
        #pragma unroll
        for (int ni = 0; ni < 2; ni++)
            #pragma unroll
            for (int ks = 0; ks < 8; ks++)
                qf[ni][ks] = *(const half8*)(xnb + (size_t)(q0 + ni*32 + m32) * DH
                                             + w*128 + ks*16 + h*8);
        FENCE();
        // stage kn[0]: wave w stages rows w*16..+15
        #pragma unroll
        for (int i = 0; i < 16; i++) {
            int r = w * 16 + i;
            const unsigned short* g = xnb + (size_t)r * DH + ((l ^ (r & 7)) * 8);
            __builtin_amdgcn_global_load_lds(
                (const __attribute__((address_space(1))) void*)g,
                (__attribute__((address_space(3))) void*)&knL[r * 512], 16, 0, 0);
        }
        FENCE();
        floatx4 vf0 = *(const floatx4*)(vptr + 0);
        floatx4 vf1 = *(const floatx4*)(vptr + 4);
        floatx4 vf2 = *(const floatx4*)(vptr + 8);
        floatx4 vf3 = *(const floatx4*)(vptr + 12);

        const unsigned short* ab0 = knL + m32 * 512;        // A row mi=0
        const unsigned short* ab1 = knL + (32 + m32) * 512; // A row mi=1
        const int ax = m32 & 7;                              // same for both rows
        const int swq = ((w * 2 + (qh >> 3)) & 3) << 1;      // W write unit-xor key

        #pragma unroll 1
        for (int t = 0; t < 65; t++) {
            if (t < 64) {
                WAITVM(4);           // kn[t] landed; V[t] (4 loads) may still fly
                BAR();               // barA
                // ---- slot1: S^T partial over K-quarter w ----
                floatx16 s00 = (floatx16)(0.f), s01 = (floatx16)(0.f);
                floatx16 s10 = (floatx16)(0.f), s11 = (floatx16)(0.f);
                __builtin_amdgcn_s_setprio(1);
                #pragma unroll
                for (int ks = 0; ks < 8; ks++) {
                    const int cl = ((w * 16 + ks * 2 + h) ^ ax) * 8;
                    half8 a0 = *(const half8*)&ab0[cl];
                    half8 a1 = *(const half8*)&ab1[cl];
                    s00 = __builtin_amdgcn_mfma_f32_32x32x16_f16(a0, qf[0][ks], s00, 0, 0, 0);
                    s01 = __builtin_amdgcn_mfma_f32_32x32x16_f16(a0, qf[1][ks], s01, 0, 0, 0);
                    s10 = __builtin_amdgcn_mfma_f32_32x32x16_f16(a1, qf[0][ks], s10, 0, 0, 0);
                    s11 = __builtin_amdgcn_mfma_f32_32x32x16_f16(a1, qf[1][ks], s11, 0, 0, 0);
                }
                __builtin_amdgcn_s_setprio(0);
                // ---- Sred writes: [w][q][kk-unit], plain units, stride-68 rows ----
                #pragma unroll
                for (int ni = 0; ni < 2; ni++) {
                    unsigned short* sp = SredL + w * 4352 + (ni * 32 + m32) * 68;
                    #pragma unroll
                    for (int rr = 0; rr < 4; rr++) {
                        const int u0 = (rr * 2 + h) * 4;        // mi=0 units
                        half4v v4a, v4b;
                        if (ni == 0) {
                            v4a[0]=(_Float16)s00[rr*4+0]; v4a[1]=(_Float16)s00[rr*4+1];
                            v4a[2]=(_Float16)s00[rr*4+2]; v4a[3]=(_Float16)s00[rr*4+3];
                            v4b[0]=(_Float16)s10[rr*4+0]; v4b[1]=(_Float16)s10[rr*4+1];
                            v4b[2]=(_Float16)s10[rr*4+2]; v4b[3]=(_Float16)s10[rr*4+3];
                        } else {
                            v4a[0]=(_Float16)s01[rr*4+0]; v4a[1]=(_Float16)s01[rr*4+1];
                            v4a[2]=(_Float16)s01[rr*4+2]; v4a[3]=(_Float16)s01[rr*4+3];
                            v4b[0]=(_Float16)s11[rr*4+0]; v4b[1]=(_Float16)s11[rr*4+1];
                            v4b[2]=(_Float16)s11[rr*4+2]; v4b[3]=(_Float16)s11[rr*4+3];
                        }
                        *(half4v*)&sp[u0]      = v4a;   // mi=0: units 0..7
                        *(half4v*)&sp[32 + u0] = v4b;   // mi=1: units 8..15
                    }
                }
                WAITLGKM();
                BAR();               // barB
                // ---- slot2: restage kn[t+1] FIRST (knL reads all done) ----
                if (t < 63) {
                    #pragma unroll
                    for (int i = 0; i < 16; i++) {
                        int r = w * 16 + i;
                        const unsigned short* g = xnb + (size_t)((t+1)*64 + r) * DH
                                                  + ((l ^ (r & 7)) * 8);
                        __builtin_amdgcn_global_load_lds(
                            (const __attribute__((address_space(1))) void*)g,
                            (__attribute__((address_space(3))) void*)&knL[r * 512], 16, 0, 0);
                    }
                    FENCE();
                }
                // ---- reduce 4 partials for (q-row w*16+qh, kk kc*16..+16) ----
                {
                    float s16[16];
                    #pragma unroll
                    for (int i = 0; i < 16; i++) s16[i] = 0.f;
                    #pragma unroll
                    for (int dh2 = 0; dh2 < 4; dh2++) {
                        const unsigned short* sp = SredL + dh2 * 4352 + (w*16 + qh) * 68 + kc * 16;
                        #pragma unroll
                        for (int un = 0; un < 4; un++) {
                            half4v p = *(const half4v*)&sp[un * 4];
                            #pragma unroll
                            for (int j = 0; j < 4; j++) s16[un*4 + j] += (float)p[j];
                        }
                    }
                    if (t < 63) { WAITVM(16); } else { WAITVM(0); }   // V[t] landed
                    half8 wlo, whi;
                    wlo[0]=(_Float16)(s16[0]*vf0[0]);  wlo[1]=(_Float16)(s16[1]*vf0[1]);
                    wlo[2]=(_Float16)(s16[2]*vf0[2]);  wlo[3]=(_Float16)(s16[3]*vf0[3]);
                    wlo[4]=(_Float16)(s16[4]*vf1[0]);  wlo[5]=(_Float16)(s16[5]*vf1[1]);
                    wlo[6]=(_Float16)(s16[6]*vf1[2]);  wlo[7]=(_Float16)(s16[7]*vf1[3]);
                    whi[0]=(_Float16)(s16[8]*vf2[0]);  whi[1]=(_Float16)(s16[9]*vf2[1]);
                    whi[2]=(_Float16)(s16[10]*vf2[2]); whi[3]=(_Float16)(s16[11]*vf2[3]);
                    whi[4]=(_Float16)(s16[12]*vf3[0]); whi[5]=(_Float16)(s16[13]*vf3[1]);
                    whi[6]=(_Float16)(s16[14]*vf3[2]); whi[7]=(_Float16)(s16[15]*vf3[3]);
                    unsigned short* wp = Wl + (t & 1) * 4608 + (size_t)(w*16 + qh) * 72;
                    *(half8*)&wp[((kc*2    ) ^ swq) * 8] = wlo;
                    *(half8*)&wp[((kc*2 + 1) ^ swq) * 8] = whi;
                }
                WAITLGKM();          // W writes + Sred reads drained before next barA
                if (t < 63) {
                    FENCE();
                    vf0 = *(const floatx4*)(vptr + (t+1)*64 + 0);
                    vf1 = *(const floatx4*)(vptr + (t+1)*64 + 4);
                    vf2 = *(const floatx4*)(vptr + (t+1)*64 + 8);
                    vf3 = *(const floatx4*)(vptr + (t+1)*64 + 12);
                    FENCE();
                }
            } else {
                BAR(); BAR();
            }
        }
        // S-group: no epilogue
    } else {
        // ================= C-group =================
        const int cw = w - 4;
        const int db = cw * 128;
        const int wsw = (m32 >> 3) << 1;     // W read unit-xor key (same for m32 and 32+m32)
        floatx16 acc[2][4];
        #pragma unroll
        for (int i = 0; i < 2; i++)
            #pragma unroll
            for (int j = 0; j < 4; j++)
                acc[i][j] = (floatx16)(0.f);
        half8 bf[4][4];

        #pragma unroll 1
        for (int t = 0; t < 65; t++) {
            if (t >= 1) {
                BAR();               // barA: W[t-1] written + drained
                // issue kt[t-1] register loads (land during S slot1)
                #pragma unroll
                for (int nd = 0; nd < 4; nd++)
                    #pragma unroll
                    for (int ks = 0; ks < 4; ks++)
                        bf[nd][ks] = *(const half8*)(xtb + (size_t)(db + nd*32 + m32) * TT
                                                     + (t-1)*64 + ks*16 + h*8);
                FENCE();
                BAR();               // barB
                WAITVM(0);
                const unsigned short* wb = Wl + ((t-1) & 1) * 4608;
                __builtin_amdgcn_s_setprio(1);
                #pragma unroll
                for (int ks = 0; ks < 4; ks++) {
                    const int uo = ((ks*2 + h) ^ wsw) * 8;
                    half8 wf0 = *(const half8*)&wb[(size_t)(m32     ) * 72 + uo];
                    half8 wf1 = *(const half8*)&wb[(size_t)(32 + m32) * 72 + uo];
                    acc[0][0] = __builtin_amdgcn_mfma_f32_32x32x16_f16(wf0, bf[0][ks], acc[0][0], 0, 0, 0);
                    acc[0][1] = __builtin_amdgcn_mfma_f32_32x32x16_f16(wf0, bf[1][ks], acc[0][1], 0, 0, 0);
                    acc[0][2] = __builtin_amdgcn_mfma_f32_32x32x16_f16(wf0, bf[2][ks], acc[0][2], 0, 0, 0);
                    acc[0][3] = __builtin_amdgcn_mfma_f32_32x32x16_f16(wf0, bf[3][ks], acc[0][3], 0, 0, 0);
                    acc[1][0] = __builtin_amdgcn_mfma_f32_32x32x16_f16(wf1, bf[0][ks], acc[1][0], 0, 0, 0);
                    acc[1][1] = __builtin_amdgcn_mfma_f32_32x32x16_f16(wf1, bf[1][ks], acc[1][1], 0, 0, 0);
                    acc[1][2] = __builtin_amdgcn_mfma_f32_32x32x16_f16(wf1, bf[2][ks], acc[1][2], 0, 0, 0);
                    acc[1][3] = __builtin_amdgcn_mfma_f32_32x32x16_f16(wf1, bf[3][ks], acc[1][3], 0, 0, 0);
                }
                __builtin_amdgcn_s_setprio(0);
            } else {
                BAR(); BAR();
            }
        }
        // ---- epilogue: out = x_left * sigmoid(ctx + bias) ----
        const float* xb = x + (size_t)b * TT * 1024;
        float* ob = out + (size_t)b * TT * DH;
        #pragma unroll
        for (int mi2 = 0; mi2 < 2; mi2++)
            #pragma unroll
            for (int nd = 0; nd < 4; nd++) {
                int d = db + nd * 32 + m32;
                float bv = bias[d];
                #pragma unroll
                for (int r = 0; r < 16; r++) {
                    int q = q0 + mi2 * 32 + (r & 3) + 8 * (r >> 2) + 4 * h;
                    float cv = acc[mi2][nd][r] + bv;
                    float gate = 1.0f / (1.0f + __expf(-cv));
                    ob[(size_t)q * DH + d] = xb[(size_t)q * 1024 + d] * gate;
                }
            }
    }
}

extern "C" void kernel_launch(void* const* d_in, const int* in_sizes, int n_in,
                              void* d_out, int out_size, void* d_ws, size_t ws_size,
                              hipStream_t stream) {
    const float* x    = (const float*)d_in[0];
    const float* V    = (const float*)d_in[1];
    const float* bias = (const float*)d_in[2];
    float* out = (float*)d_out;

    unsigned short* xn  = (unsigned short*)d_ws;              // [4][4096][512] fp16
    unsigned short* xnT = xn + (size_t)4 * TT * DH;           // [4][512][4096] fp16

    norm_k<<<dim3(4 * TT / 4), 256, 0, stream>>>(x, xn);
    transpose_k<<<dim3(TT / 64, DH / 64, 4), 256, 0, stream>>>(xn, xnT);
    fused_k<<<dim3(TT / 64, 4), 512, 0, stream>>>(xn, xnT, V, bias, x, out);
}

// Round 6
// 200.190 us; speedup vs baseline: 2.5362x; 2.5362x over previous
//
#include <hip/hip_runtime.h>
#include <stdint.h>

typedef _Float16 half8 __attribute__((ext_vector_type(8)));
typedef _Float16 half4v __attribute__((ext_vector_type(4)));
typedef float floatx4 __attribute__((ext_vector_type(4)));
typedef float floatx16 __attribute__((ext_vector_type(16)));

#define TT 4096
#define DH 512

#define WAITLGKM() asm volatile("s_waitcnt lgkmcnt(0)" ::: "memory")
#define BAR() __builtin_amdgcn_s_barrier()
#define FENCE() asm volatile("" ::: "memory")

__device__ __forceinline__ unsigned short f2h(float f) {
    union { _Float16 h; unsigned short u; } v;
    v.h = (_Float16)f;
    return v.u;
}

// ---------- kernel 1: normalize right half of x -> xn (fp16), one wave per row ----------
__global__ void norm_k(const float* __restrict__ x, unsigned short* __restrict__ xn) {
    const int w = threadIdx.x >> 6, l = threadIdx.x & 63;
    const int row = blockIdx.x * 4 + w;              // 0 .. B*T-1
    const float* src = x + (size_t)row * 1024 + 512 + l * 8;
    floatx4 a = *(const floatx4*)src;
    floatx4 c = *(const floatx4*)(src + 4);
    float s = a[0]*a[0] + a[1]*a[1] + a[2]*a[2] + a[3]*a[3]
            + c[0]*c[0] + c[1]*c[1] + c[2]*c[2] + c[3]*c[3];
    #pragma unroll
    for (int off = 32; off > 0; off >>= 1) s += __shfl_xor(s, off);
    const float scale = 1.0f / fmaxf(sqrtf(s), 1e-12f);
    float v[8] = {a[0], a[1], a[2], a[3], c[0], c[1], c[2], c[3]};
    uint32_t pk[4];
    #pragma unroll
    for (int i = 0; i < 4; i++)
        pk[i] = (uint32_t)f2h(v[2*i] * scale) | ((uint32_t)f2h(v[2*i+1] * scale) << 16);
    uint4 o; o.x = pk[0]; o.y = pk[1]; o.z = pk[2]; o.w = pk[3];
    *(uint4*)(xn + (size_t)row * DH + l * 8) = o;
}

// ---------- kernel 2: xnT[b][d][t] = xn[b][t][d], 64x64 LDS tile transpose ----------
__global__ void transpose_k(const unsigned short* __restrict__ xn,
                            unsigned short* __restrict__ xnT) {
    __shared__ __align__(16) unsigned short tile[64 * 72];  // +8 pad
    const int b = blockIdx.z;
    const int t0 = blockIdx.x * 64, d0 = blockIdx.y * 64;
    const int tid = threadIdx.x;
    #pragma unroll
    for (int i = 0; i < 2; i++) {
        int c = i * 256 + tid;
        int tr = c >> 3, d8 = c & 7;
        uint4 vv = *(const uint4*)(xn + ((size_t)(b * TT + t0 + tr) * DH + d0 + d8 * 8));
        *(uint4*)&tile[tr * 72 + d8 * 8] = vv;
    }
    __syncthreads();
    #pragma unroll
    for (int i = 0; i < 2; i++) {
        int c = i * 256 + tid;
        int dd = c >> 3, t8 = c & 7;
        uint32_t pk[4];
        #pragma unroll
        for (int k = 0; k < 4; k++) {
            uint32_t h0 = tile[(t8 * 8 + 2 * k    ) * 72 + dd];
            uint32_t h1 = tile[(t8 * 8 + 2 * k + 1) * 72 + dd];
            pk[k] = h0 | (h1 << 16);
        }
        uint4 o; o.x = pk[0]; o.y = pk[1]; o.z = pk[2]; o.w = pk[3];
        *(uint4*)(xnT + ((size_t)(b * DH + d0 + dd) * TT + t0 + t8 * 8)) = o;
    }
}

// ---------- kernel 3: homogeneous 8-wave fused kernel ----------
// Wave w: step1 role (g=w>>2, mi=(w>>1)&1, dh=w&1): S^T partial p=g*2+dh for its
//   32 kk rows (mi) over k-128; step3/epilogue role: d-slice [w*64, w*64+64).
// kn slice [32kk][128d] and kt slice [64d][64kk] are WAVE-PRIVATE (gll-staged,
//   chunk-XOR pre-swizzled at source) -> no barriers for staging, counted vmcnt only.
// Per tile: vmcnt(10) | step1 (8 rd, 16 mfma) | Sred wr | lgkm | issue kn[t+1] | BAR_B
//   | reduce (4 rd) vmcnt(8) | lgkm BAR_mid | W wr | lgkm BAR_C
//   | step3 (16 rd, 16 mfma) | lgkm | issue kt[t+1],V[t+1] | BAR_D
// LDS 160KiB exact: kn 64 | kt 64 | Sred[4][64][64] 32 (W[64][72] overlaid).
__global__ __launch_bounds__(512, 2) void fused_k(
    const unsigned short* __restrict__ xn, const unsigned short* __restrict__ xnT,
    const float* __restrict__ V, const float* __restrict__ bias,
    const float* __restrict__ x, float* __restrict__ out)
{
    __shared__ __align__(16) unsigned short smem[81920];   // 160 KiB exact
    unsigned short* knB   = smem;            // [8 w][32 kk][128 d]
    unsigned short* ktB   = smem + 32768;    // [8 w][64 d][64 kk]
    unsigned short* SredL = smem + 65536;    // [4 p][64 q][64 kk]
    unsigned short* Wl    = SredL;           // overlay [64 q][72]

    const int tid = threadIdx.x;
    const int w = tid >> 6, l = tid & 63;
    const int h = l >> 5, m32 = l & 31;
    const int g = w >> 2, mi = (w >> 1) & 1, dh = w & 1;
    const int p = g * 2 + dh;
    const int wk0 = g * 256 + dh * 128;      // step1 k-range base
    const int wd0 = w * 64;                  // step3 d-slice base

    // XCD-aware swizzle
    const int flat = blockIdx.y * 64 + blockIdx.x;
    const int work = (flat & 7) * 32 + (flat >> 3);
    const int b = work >> 6, qt = work & 63;
    const int q0 = qt * 64;

    const unsigned short* xnb = xn  + (size_t)b * TT * DH;
    const unsigned short* xtb = xnT + (size_t)b * DH * TT;

    unsigned short* knP = knB + w * 4096;
    unsigned short* ktP = ktB + w * 4096;

    // reduce-phase mapping: q-row tq, kk chunk to*8
    const int tq = tid >> 3, to = tid & 7;
    const float* vptr = V + (size_t)(q0 + tq) * TT + to * 8;
    const int rsw = ((to * 2) ^ ((tq & 7) << 1)) * 4;   // Sred read unit offset (u16)

    // ---- prologue: Q fragments (B-operand): lane q=q0+ni*32+m32, k=wk0+ks*16+h*8+j
    half8 qf[2][8];
    #pragma unroll
    for (int ni = 0; ni < 2; ni++)
        #pragma unroll
        for (int ks = 0; ks < 8; ks++)
            qf[ni][ks] = *(const half8*)(xnb + (size_t)(q0 + ni*32 + m32) * DH
                                         + wk0 + ks*16 + h*8);
    FENCE();
    // stage kn[0]: 8 gll, 4 rows each
    #pragma unroll
    for (int i = 0; i < 8; i++) {
        int r = i * 4 + (l >> 4);                        // local kk row 0..31
        int c = (l & 15) ^ (r & 7);                      // pre-swizzled global chunk
        const unsigned short* gp = xnb + (size_t)(mi*32 + r) * DH + wk0 + c * 8;
        __builtin_amdgcn_global_load_lds(
            (const __attribute__((address_space(1))) void*)gp,
            (__attribute__((address_space(3))) void*)&knP[i * 512], 16, 0, 0);
    }
    FENCE();
    // stage kt[0]: 8 gll, 8 d-rows each
    #pragma unroll
    for (int i = 0; i < 8; i++) {
        int dr = i * 8 + (l >> 3);                       // local d row 0..63
        int c = (l & 7) ^ (dr & 7);
        const unsigned short* gp = xtb + (size_t)(wd0 + dr) * TT + c * 8;
        __builtin_amdgcn_global_load_lds(
            (const __attribute__((address_space(1))) void*)gp,
            (__attribute__((address_space(3))) void*)&ktP[i * 512], 16, 0, 0);
    }
    FENCE();
    floatx4 vf0 = *(const floatx4*)(vptr);
    floatx4 vf1 = *(const floatx4*)(vptr + 4);

    floatx16 acc[2][2];
    #pragma unroll
    for (int i = 0; i < 2; i++)
        #pragma unroll
        for (int j = 0; j < 2; j++)
            acc[i][j] = (floatx16)(0.f);

    #pragma unroll 1
    for (int t = 0; t < 64; t++) {
        // ---- kn[t] landed (kt[t] 8 + V[t] 2 stay in flight) ----
        asm volatile("s_waitcnt vmcnt(10)" ::: "memory");

        // ---- step1: S^T partial p, rows mi, k-128; 8 reads, 16 mfma ----
        floatx16 s0 = (floatx16)(0.f), s1 = (floatx16)(0.f);
        __builtin_amdgcn_s_setprio(1);
        #pragma unroll
        for (int ks = 0; ks < 8; ks++) {
            half8 a = *(const half8*)&knP[m32 * 128 + (((ks*2 + h) ^ (m32 & 7)) * 8)];
            s0 = __builtin_amdgcn_mfma_f32_32x32x16_f16(a, qf[0][ks], s0, 0, 0, 0);
            s1 = __builtin_amdgcn_mfma_f32_32x32x16_f16(a, qf[1][ks], s1, 0, 0, 0);
        }
        __builtin_amdgcn_s_setprio(0);

        // ---- Sred write: [p][q][kk], unit4 ^ ((q&7)<<1) ----
        #pragma unroll
        for (int ni = 0; ni < 2; ni++) {
            const int q = ni * 32 + m32;
            unsigned short* sp = SredL + p * 4096 + q * 64;
            const int sw = (q & 7) << 1;
            #pragma unroll
            for (int rr = 0; rr < 4; rr++) {
                int u = (mi * 8 + rr * 2 + h) ^ sw;
                half4v v4;
                if (ni == 0) {
                    v4[0]=(_Float16)s0[rr*4+0]; v4[1]=(_Float16)s0[rr*4+1];
                    v4[2]=(_Float16)s0[rr*4+2]; v4[3]=(_Float16)s0[rr*4+3];
                } else {
                    v4[0]=(_Float16)s1[rr*4+0]; v4[1]=(_Float16)s1[rr*4+1];
                    v4[2]=(_Float16)s1[rr*4+2]; v4[3]=(_Float16)s1[rr*4+3];
                }
                *(half4v*)&sp[u * 4] = v4;
            }
        }
        WAITLGKM();
        // ---- issue kn[t+1] (private slice free now) ----
        if (t < 63) {
            #pragma unroll
            for (int i = 0; i < 8; i++) {
                int r = i * 4 + (l >> 4);
                int c = (l & 15) ^ (r & 7);
                const unsigned short* gp = xnb + (size_t)((t+1)*64 + mi*32 + r) * DH + wk0 + c * 8;
                __builtin_amdgcn_global_load_lds(
                    (const __attribute__((address_space(1))) void*)gp,
                    (__attribute__((address_space(3))) void*)&knP[i * 512], 16, 0, 0);
            }
            FENCE();
        }
        BAR();   // BAR_B: Sred complete

        // ---- reduce: 4 partials (fp16 adds), *V ----
        half8 pr0 = *(const half8*)&SredL[        tq * 64 + rsw];
        half8 pr1 = *(const half8*)&SredL[4096  + tq * 64 + rsw];
        half8 pr2 = *(const half8*)&SredL[8192  + tq * 64 + rsw];
        half8 pr3 = *(const half8*)&SredL[12288 + tq * 64 + rsw];
        half8 sum = (pr0 + pr1) + (pr2 + pr3);
        if (t < 63) { asm volatile("s_waitcnt vmcnt(8)" ::: "memory"); }
        else        { asm volatile("s_waitcnt vmcnt(0)" ::: "memory"); }
        half8 wv;
        wv[0]=(_Float16)((float)sum[0]*vf0[0]); wv[1]=(_Float16)((float)sum[1]*vf0[1]);
        wv[2]=(_Float16)((float)sum[2]*vf0[2]); wv[3]=(_Float16)((float)sum[3]*vf0[3]);
        wv[4]=(_Float16)((float)sum[4]*vf1[0]); wv[5]=(_Float16)((float)sum[5]*vf1[1]);
        wv[6]=(_Float16)((float)sum[6]*vf1[2]); wv[7]=(_Float16)((float)sum[7]*vf1[3]);
        WAITLGKM();
        BAR();   // BAR_mid: all Sred reads done -> W overlay write safe
        *(half8*)&Wl[tq * 72 + to * 8] = wv;
        WAITLGKM();
        BAR();   // BAR_C: W ready

        // ---- step3: ctx[q][wd0..+64] += W * Kn ; 16 reads, 16 mfma ----
        __builtin_amdgcn_s_setprio(1);
        #pragma unroll
        for (int ks = 0; ks < 4; ks++) {
            half8 wf0 = *(const half8*)&Wl[(m32     ) * 72 + ks*16 + h*8];
            half8 wf1 = *(const half8*)&Wl[(32 + m32) * 72 + ks*16 + h*8];
            half8 kf0 = *(const half8*)&ktP[(m32     ) * 64 + (((ks*2+h) ^ (m32 & 7)) * 8)];
            half8 kf1 = *(const half8*)&ktP[(32 + m32) * 64 + (((ks*2+h) ^ (m32 & 7)) * 8)];
            acc[0][0] = __builtin_amdgcn_mfma_f32_32x32x16_f16(wf0, kf0, acc[0][0], 0, 0, 0);
            acc[0][1] = __builtin_amdgcn_mfma_f32_32x32x16_f16(wf0, kf1, acc[0][1], 0, 0, 0);
            acc[1][0] = __builtin_amdgcn_mfma_f32_32x32x16_f16(wf1, kf0, acc[1][0], 0, 0, 0);
            acc[1][1] = __builtin_amdgcn_mfma_f32_32x32x16_f16(wf1, kf1, acc[1][1], 0, 0, 0);
        }
        __builtin_amdgcn_s_setprio(0);
        WAITLGKM();
        // ---- issue kt[t+1] + V[t+1] (private; cover = next step1+reduce) ----
        if (t < 63) {
            #pragma unroll
            for (int i = 0; i < 8; i++) {
                int dr = i * 8 + (l >> 3);
                int c = (l & 7) ^ (dr & 7);
                const unsigned short* gp = xtb + (size_t)(wd0 + dr) * TT + (t+1)*64 + c * 8;
                __builtin_amdgcn_global_load_lds(
                    (const __attribute__((address_space(1))) void*)gp,
                    (__attribute__((address_space(3))) void*)&ktP[i * 512], 16, 0, 0);
            }
            FENCE();
            vf0 = *(const floatx4*)(vptr + (t+1)*64);
            vf1 = *(const floatx4*)(vptr + (t+1)*64 + 4);
            FENCE();
        }
        BAR();   // BAR_D: step3 reads done -> Sred/W reusable next tile
    }

    // ---- epilogue: out = x_left * sigmoid(ctx + bias) ----
    const float* xb = x + (size_t)b * TT * 1024;
    float* ob = out + (size_t)b * TT * DH;
    #pragma unroll
    for (int mi2 = 0; mi2 < 2; mi2++)
        #pragma unroll
        for (int nd = 0; nd < 2; nd++) {
            int d = wd0 + nd * 32 + m32;
            float bv = bias[d];
            #pragma unroll
            for (int r = 0; r < 16; r++) {
                int q = q0 + mi2 * 32 + (r & 3) + 8 * (r >> 2) + 4 * h;
                float cv = acc[mi2][nd][r] + bv;
                float gate = 1.0f / (1.0f + __expf(-cv));
                ob[(size_t)q * DH + d] = xb[(size_t)q * 1024 + d] * gate;
            }
        }
}

extern "C" void kernel_launch(void* const* d_in, const int* in_sizes, int n_in,
                              void* d_out, int out_size, void* d_ws, size_t ws_size,
                              hipStream_t stream) {
    const float* x    = (const float*)d_in[0];
    const float* V    = (const float*)d_in[1];
    const float* bias = (const float*)d_in[2];
    float* out = (float*)d_out;

    unsigned short* xn  = (unsigned short*)d_ws;              // [4][4096][512] fp16
    unsigned short* xnT = xn + (size_t)4 * TT * DH;           // [4][512][4096] fp16

    norm_k<<<dim3(4 * TT / 4), 256, 0, stream>>>(x, xn);
    transpose_k<<<dim3(TT / 64, DH / 64, 4), 256, 0, stream>>>(xn, xnT);
    fused_k<<<dim3(TT / 64, 4), 512, 0, stream>>>(xn, xnT, V, bias, x, out);
}